// Round 1
// 1306.366 us; speedup vs baseline: 2.4393x; 2.4393x over previous
//
#include <hip/hip_runtime.h>

#define B_ 4
#define C_ 4
#define T_ 4096
#define H_ 256
#define INNER_ 512
#define S_ 64
#define L_ 3
#define V_ 1024
#define NTOK (B_*T_)   // 16384
#define TPAD (T_+24)   // 4120: 12 zero rows each side per batch

typedef __attribute__((ext_vector_type(8))) short short8v;
typedef __attribute__((ext_vector_type(4))) float f32x4;

__device__ __forceinline__ float siluf(float x) { return x / (1.0f + expf(-x)); }

__device__ __forceinline__ unsigned short f2bf(float x) {
    unsigned u = __float_as_uint(x);
    u = (u + 0x7FFFu + ((u >> 16) & 1u)) >> 16;   // RNE
    return (unsigned short)u;
}
__device__ __forceinline__ float bf2f(unsigned short v) {
    return __uint_as_float(((unsigned)v) << 16);
}

// ============================ bf16 MFMA GEMM ==========================================
// C(N,M) = A(N,K) * Bw(M,K)^T, A/B bf16, accum fp32. Tile 128 x BN, BK=32, 4 waves.
// LDS is fragment-major: frag f = 1KB, lane l reads its 8 contiguous k at f*1024+l*16
// (ds_read_b128, conflict-free); staging writes the matching permutation (conflict-free).
// flags: 1=accumulate into C (fp32), 2=C stored bf16, 4=head epilogue (remap + bias).
// bstride/roff: batch-padded A addressing (row = (n0>>12)*bstride + (n0&4095) + roff).
// patmode: 1/2 = dilated-pattern shifted GEMM (blockIdx.y=dil group, k-tap 0 / 2).
template<int BN>
__global__ __launch_bounds__(256) void gemm_mfma(
    const unsigned short* __restrict__ Ag, int lda,
    const unsigned short* __restrict__ Bg, int ldb,
    float* __restrict__ Cg, int ldc,
    int K, int flags, const float* __restrict__ bias,
    int bstride, int roff, int patmode)
{
    constexpr int FM  = (BN == 128) ? 4 : 2;
    constexpr int FN  = 4;
    constexpr int BCH = (BN == 128) ? 2 : 1;
    __shared__ __attribute__((aligned(16))) unsigned short Alds[128 * 32];
    __shared__ __attribute__((aligned(16))) unsigned short Blds[BN * 32];

    int tid = threadIdx.x;
    int wid = tid >> 6, lane = tid & 63;
    int qq = lane >> 4, l16 = lane & 15;
    int wm, wn;
    if (BN == 128) { wm = wid >> 1; wn = wid & 1; } else { wm = wid; wn = 0; }

    int n0 = blockIdx.x * 128;
    int m0; const unsigned short* Bp; float* Cb; int ro = roff;
    if (patmode) {
        int g = blockIdx.y;                       // dilation group 0..3
        int d = (g == 0) ? 1 : (g == 1) ? 3 : (g == 2) ? 6 : 12;
        ro = 12 + ((patmode == 1) ? -d : d);      // tap 0 -> -d, tap 2 -> +d
        m0 = 0;
        Bp = Bg + (size_t)((g << 1) + (patmode - 1)) * (64 * 256);
        Cb = Cg + g * 64;
    } else {
        m0 = blockIdx.y * BN; Bp = Bg; Cb = Cg;
    }
    const unsigned short* Ab = Ag +
        (size_t)(bstride ? ((n0 >> 12) * bstride + (n0 & (T_ - 1)) + ro) : n0) * lda;

    f32x4 acc[FM][FN] = {};

    for (int k0 = 0; k0 < K; k0 += 32) {
        short8v av[2], bv[BCH];
#pragma unroll
        for (int it = 0; it < 2; ++it) {
            int u = tid + (it << 8);
            int row = u >> 2, cb = u & 3;
            av[it] = *(const short8v*)(Ab + (size_t)row * lda + k0 + cb * 8);
        }
#pragma unroll
        for (int it = 0; it < BCH; ++it) {
            int u = tid + (it << 8);
            int row = u >> 2, cb = u & 3;
            bv[it] = *(const short8v*)(Bp + (size_t)(m0 + row) * ldb + k0 + cb * 8);
        }
        __syncthreads();   // previous iteration's frag reads done
#pragma unroll
        for (int it = 0; it < 2; ++it) {
            int u = tid + (it << 8);
            int row = u >> 2, cb = u & 3;
            *(short8v*)(Alds + (row >> 4) * 512 + cb * 128 + (row & 15) * 8) = av[it];
        }
#pragma unroll
        for (int it = 0; it < BCH; ++it) {
            int u = tid + (it << 8);
            int row = u >> 2, cb = u & 3;
            *(short8v*)(Blds + (row >> 4) * 512 + cb * 128 + (row & 15) * 8) = bv[it];
        }
        __syncthreads();
        short8v afr[FM], bfr[FN];
#pragma unroll
        for (int i = 0; i < FM; ++i)
            afr[i] = *(const short8v*)(Alds + (wm * FM + i) * 512 + lane * 8);
#pragma unroll
        for (int j = 0; j < FN; ++j)
            bfr[j] = *(const short8v*)(Blds + (wn * FN + j) * 512 + lane * 8);
#pragma unroll
        for (int i = 0; i < FM; ++i)
#pragma unroll
            for (int j = 0; j < FN; ++j)
                acc[i][j] = __builtin_amdgcn_mfma_f32_16x16x32_bf16(afr[i], bfr[j], acc[i][j], 0, 0, 0);
    }

#pragma unroll
    for (int i = 0; i < FM; ++i) {
#pragma unroll
        for (int r = 0; r < 4; ++r) {
            int row = n0 + wm * (FM * 16) + i * 16 + qq * 4 + r;
#pragma unroll
            for (int j = 0; j < FN; ++j) {
                int col = m0 + wn * (FN * 16) + j * 16 + l16;
                float v = acc[i][j][r];
                if (bias) v += bias[col];
                if (flags & 4) {                       // head: out[b,c,t,v]
                    int bb2 = row >> 12, t = row & (T_ - 1);
                    int cc = col >> 10, vv = col & (V_ - 1);
                    Cg[((size_t)(((bb2 << 2) + cc) << 12) + t) * V_ + vv] = v;
                } else if (flags & 2) {                // bf16 C
                    ((unsigned short*)Cb)[(size_t)row * ldc + col] = f2bf(v);
                } else if (flags & 1) {                // accumulate fp32
                    float* p = Cb + (size_t)row * ldc + col;
                    *p = *p + v;
                } else {
                    Cb[(size_t)row * ldc + col] = v;
                }
            }
        }
    }
}

// ---------------- embedding: fp32 A + bf16 padded copy for GEMM/pat --------------------
__global__ __launch_bounds__(256) void k_embed(
    const int* __restrict__ tok, const float* __restrict__ text,
    const float* __restrict__ tok_emb, const float* __restrict__ pos_emb,
    const int* __restrict__ pos_off, float* __restrict__ A, unsigned short* __restrict__ Apad)
{
    int gid = blockIdx.x * 256 + threadIdx.x;
    int h = gid & (H_ - 1);
    int n = gid >> 8;
    int b = n >> 12, t = n & (T_ - 1);
    float acc = 0.f;
#pragma unroll
    for (int c = 0; c < C_; ++c) {
        int tk = tok[((b * C_ + c) << 12) + t];
        acc += tok_emb[(c * V_ + tk) * H_ + h];
    }
    int po = pos_off[0];
    acc = acc * 0.25f + pos_emb[(po + t) * H_ + h] + text[b * H_ + h];
    A[(size_t)n * H_ + h] = acc;
    Apad[((size_t)b * TPAD + 12 + t) * H_ + h] = f2bf(acc);
}

__global__ void k_zeropad(unsigned short* __restrict__ Apad)
{
    int blk = blockIdx.x;                 // 96 = 4 batches * 24 pad rows
    int b = blk / 24, rw = blk % 24;
    int rr = rw < 12 ? rw : T_ + rw;      // rows 0..11 and 4108..4119
    Apad[((size_t)b * TPAD + rr) * H_ + threadIdx.x] = 0;
}

// ---------------- all weight fp32 -> bf16 conversions in one kernel --------------------
__global__ __launch_bounds__(256) void k_wconv(
    const float* __restrict__ inw, const float* __restrict__ outw,
    const float* __restrict__ bpw, const float* __restrict__ fusw,
    const float* __restrict__ headw,
    unsigned short* __restrict__ dinw, unsigned short* __restrict__ doutw,
    unsigned short* __restrict__ dbpw, unsigned short* __restrict__ dfusw,
    unsigned short* __restrict__ dheadw)
{
    int i = blockIdx.x * 256 + threadIdx.x;       // total 2,457,600
    if (i < 786432)        dinw[i] = f2bf(inw[i]);
    else if (i < 1179648)  doutw[i - 786432]  = f2bf(outw[i - 786432]);
    else if (i < 1277952)  dbpw[i - 1179648]  = f2bf(bpw[i - 1179648]);
    else if (i < 1409024)  dfusw[i - 1277952] = f2bf(fusw[i - 1277952]);
    else                   dheadw[i - 1409024] = f2bf(headw[i - 1409024]);
}

// pack pat weights: w0[oc][cin] = pw[...,k=1]; wk[g][o][cin], g = id*2 + (k==2)
__global__ __launch_bounds__(256) void k_pack_pat(
    const float* __restrict__ pw, unsigned short* __restrict__ w0,
    unsigned short* __restrict__ wk)
{
    int idx = blockIdx.x * 256 + threadIdx.x;     // 65536 + 131072
    if (idx < 65536) {
        int oc = idx >> 8, cin = idx & 255;
        w0[idx] = f2bf(pw[(oc * 256 + cin) * 3 + 1]);
    } else {
        int j = idx - 65536;
        int g = j >> 14, o = (j >> 8) & 63, cin = j & 255;
        int id = g >> 1, kk = (g & 1) * 2;
        wk[j] = f2bf(pw[((id * 64 + o) * 256 + cin) * 3 + kk]);
    }
}

// ---------------- causal depthwise conv4 + bias + silu (bf16 in/out) -------------------
__global__ __launch_bounds__(256) void k_conv(
    const unsigned short* __restrict__ XPb, const float* __restrict__ cw,
    const float* __restrict__ cb, unsigned short* __restrict__ XCb)
{
    int gid = blockIdx.x * 256 + threadIdx.x;
    int i = gid & (INNER_ - 1);
    int n = gid >> 9;
    int b = n >> 12, t = n & (T_ - 1);
    float acc = cb[i];
#pragma unroll
    for (int k = 0; k < 4; ++k) {
        int tt = t - 3 + k;
        if (tt >= 0) acc += bf2f(XPb[(size_t)((b << 12) + tt) * 1024 + i]) * cw[i * 4 + k];
    }
    XCb[(size_t)n * INNER_ + i] = f2bf(siluf(acc));
}

// ---------------- chunked parallel EWMA scan -------------------------------------------
__global__ void k_scan_local(float* __restrict__ U, float* __restrict__ hend)
{
    int blk = blockIdx.x;                 // 256 = 4 batches * 64 chunks
    int b = blk >> 6, c = blk & 63;
    int s = threadIdx.x;                  // 64
    float* p = U + ((size_t)(b << 12) + c * 64) * 64 + s;
    float h = 0.f;
#pragma unroll 4
    for (int t = 0; t < 64; ++t) { h = 0.95f * h + 0.05f * p[t * 64]; p[t * 64] = h; }
    hend[(size_t)blk * 64 + s] = h;
}

__global__ void k_scan_apply(float* __restrict__ U, const float* __restrict__ hend)
{
    int blk = blockIdx.x;
    int b = blk >> 6, c = blk & 63;
    int s = threadIdx.x;
    if (c == 0) return;
    const float F = 0.03752414f;          // 0.95^64
    float Hc = 0.f;
    for (int cc = 0; cc < c; ++cc) Hc = hend[(size_t)((b << 6) + cc) * 64 + s] + F * Hc;
    float* p = U + ((size_t)(b << 12) + c * 64) * 64 + s;
    float w = 0.95f;
#pragma unroll 4
    for (int t = 0; t < 64; ++t) { p[t * 64] += w * Hc; w *= 0.95f; }
}

// ---------------- y2 = (hs@Cp^T + D*xc) * silu(xg), bf16 in place over XC --------------
__global__ __launch_bounds__(256) void k_ymix(
    const float* __restrict__ HS, const float* __restrict__ Cp,
    const float* __restrict__ Dp, unsigned short* __restrict__ XCb,
    const unsigned short* __restrict__ XPb)
{
    const int NB = 4;
    int n0 = blockIdx.x * NB;
    __shared__ float hsL[NB * 64];
    int tid = threadIdx.x;
    {
        int nn = tid >> 6, s = tid & 63;
        hsL[tid] = HS[(size_t)(n0 + nn) * 64 + s];
    }
    __syncthreads();
#pragma unroll
    for (int half = 0; half < 2; ++half) {
        int i = tid + half * 256;
        float acc[NB] = {};
        const float* cp = Cp + i * 64;
        for (int s = 0; s < 64; ++s) {
            float w = cp[s];
#pragma unroll
            for (int nn = 0; nn < NB; ++nn) acc[nn] += hsL[nn * 64 + s] * w;
        }
        float d = Dp[i];
#pragma unroll
        for (int nn = 0; nn < NB; ++nn) {
            size_t n = n0 + nn;
            float xc = bf2f(XCb[n * INNER_ + i]);
            float xg = bf2f(XPb[n * 1024 + 512 + i]);
            XCb[n * INNER_ + i] = f2bf((acc[nn] + d * xc) * siluf(xg));
        }
    }
}

// ---------------- residual + LayerNorm, fp32 out + bf16 copy ---------------------------
__global__ __launch_bounds__(256) void k_ln(
    const float* __restrict__ Yo, const float* __restrict__ Xin,
    const float* __restrict__ g, const float* __restrict__ bb,
    float* __restrict__ Out, unsigned short* __restrict__ Obf, int obfld)
{
    int n = blockIdx.x, h = threadIdx.x;
    float x = Yo[(size_t)n * H_ + h] + Xin[(size_t)n * H_ + h];
    float s = x, sq = x * x;
#pragma unroll
    for (int off = 32; off >= 1; off >>= 1) {
        s  += __shfl_down(s, off, 64);
        sq += __shfl_down(sq, off, 64);
    }
    __shared__ float rs[4], rq[4];
    int wid = h >> 6, lane = h & 63;
    if (lane == 0) { rs[wid] = s; rq[wid] = sq; }
    __syncthreads();
    float S = rs[0] + rs[1] + rs[2] + rs[3];
    float Q = rq[0] + rq[1] + rq[2] + rq[3];
    float m = S * (1.f / H_);
    float v = fmaxf(Q * (1.f / H_) - m * m, 0.f);
    float r = rsqrtf(v + 1e-5f);
    float y = (x - m) * r * g[h] + bb[h];
    Out[(size_t)n * H_ + h] = y;
    Obf[(size_t)n * obfld + h] = f2bf(y);
}

// ---------------- relu(pre + fus_b) then LN, bf16 out ----------------------------------
__global__ __launch_bounds__(256) void k_fusln(
    const float* __restrict__ Pre, const float* __restrict__ fb,
    const float* __restrict__ fg, const float* __restrict__ fbb,
    unsigned short* __restrict__ Outb)
{
    int n = blockIdx.x, h = threadIdx.x;
    float x = fmaxf(Pre[(size_t)n * H_ + h] + fb[h], 0.f);
    float s = x, sq = x * x;
#pragma unroll
    for (int off = 32; off >= 1; off >>= 1) {
        s  += __shfl_down(s, off, 64);
        sq += __shfl_down(sq, off, 64);
    }
    __shared__ float rs[4], rq[4];
    int wid = h >> 6, lane = h & 63;
    if (lane == 0) { rs[wid] = s; rq[wid] = sq; }
    __syncthreads();
    float S = rs[0] + rs[1] + rs[2] + rs[3];
    float Q = rq[0] + rq[1] + rq[2] + rq[3];
    float m = S * (1.f / H_);
    float v = fmaxf(Q * (1.f / H_) - m * m, 0.f);
    float r = rsqrtf(v + 1e-5f);
    Outb[(size_t)n * H_ + h] = f2bf((x - m) * r * fg[h] + fbb[h]);
}

// ---------------- PAT fp32 -> COMB bf16 cols 256..511 ----------------------------------
__global__ __launch_bounds__(256) void k_pat2comb(
    const float* __restrict__ PAT, unsigned short* __restrict__ COMB)
{
    int i = blockIdx.x * 256 + threadIdx.x;   // 16384*256
    int n = i >> 8, h = i & 255;
    COMB[(size_t)n * 512 + 256 + h] = f2bf(PAT[i]);
}

extern "C" void kernel_launch(void* const* d_in, const int* in_sizes, int n_in,
                              void* d_out, int out_size, void* d_ws, size_t ws_size,
                              hipStream_t stream)
{
    (void)in_sizes; (void)n_in; (void)out_size; (void)ws_size;
    const int*   tok      = (const int*)d_in[0];
    const float* text     = (const float*)d_in[1];
    const float* tok_emb  = (const float*)d_in[2];
    const float* pos_emb  = (const float*)d_in[3];
    const float* in_w     = (const float*)d_in[4];
    const float* conv_w   = (const float*)d_in[5];
    const float* conv_b   = (const float*)d_in[6];
    const float* Dw       = (const float*)d_in[7];
    const float* Bp_w     = (const float*)d_in[8];
    const float* Cp_w     = (const float*)d_in[9];
    const float* out_w    = (const float*)d_in[10];
    const float* ln_g     = (const float*)d_in[11];
    const float* ln_b     = (const float*)d_in[12];
    const float* pat_w    = (const float*)d_in[13];
    const float* pat_b    = (const float*)d_in[14];
    const float* fus_w    = (const float*)d_in[15];
    const float* fus_b    = (const float*)d_in[16];
    const float* fus_g    = (const float*)d_in[17];
    const float* fus_bb   = (const float*)d_in[18];
    const float* head_w   = (const float*)d_in[19];
    const float* head_b   = (const float*)d_in[20];
    const int*   pos_off  = (const int*)d_in[21];

    float* W = (float*)d_ws;
    float* Abuf = W;                                              // 4,194,304 f
    float* F0   = W + 4194304;                                    // 4,194,304 f
    float* F1   = W + 8388608;                                    // 4,194,304 f
    float* U    = W + 12582912;                                   // 1,048,576 f
    float* HEND = W + 13631488;                                   //    16,384 f
    unsigned short* XPbf = (unsigned short*)(W + 13647872);       // 16,777,216 bf16
    unsigned short* XCbf = (unsigned short*)(W + 22036480);       //  8,388,608 bf16
    unsigned short* Fbf  = (unsigned short*)(W + 26230784);       //  4,194,304 bf16
    unsigned short* COMB = (unsigned short*)(W + 28327936);       //  8,388,608 bf16
    unsigned short* Apad = (unsigned short*)(W + 32522240);       //  4,218,880 bf16
    float* PATF = W + 13647872;            // reuse XPbf region (dead after mamba loop)
    float* FUSP = W + 13647872 + 4194304;  // next 4.19Mf of XPbf region
    unsigned short* inwb   = (unsigned short*)(W + 34631680);     //   786,432 bf16
    unsigned short* outwb  = (unsigned short*)(W + 35024896);     //   393,216 bf16
    unsigned short* bpwb   = (unsigned short*)(W + 35221504);     //    98,304 bf16
    unsigned short* fuswb  = (unsigned short*)(W + 35270656);     //   131,072 bf16
    unsigned short* headwb = (unsigned short*)(W + 35336192);     // 1,048,576 bf16
    unsigned short* w0b    = (unsigned short*)(W + 35860480);     //    65,536 bf16
    unsigned short* wkb    = (unsigned short*)(W + 35893248);     //   131,072 bf16
    // total 35,958,784 floats = 137.2 MiB

    k_embed<<<NTOK * H_ / 256, 256, 0, stream>>>(tok, text, tok_emb, pos_emb, pos_off, Abuf, Apad);
    k_zeropad<<<96, 256, 0, stream>>>(Apad);
    k_wconv<<<9600, 256, 0, stream>>>(in_w, out_w, Bp_w, fus_w, head_w,
                                      inwb, outwb, bpwb, fuswb, headwb);
    k_pack_pat<<<768, 256, 0, stream>>>(pat_w, w0b, wkb);

    const float* fin = Abuf;
    float* fouts[3] = {F0, F1, F0};
    for (int l = 0; l < L_; ++l) {
        const unsigned short* Ain = (l == 0) ? Apad : Fbf;
        gemm_mfma<128><<<dim3(128, 8), 256, 0, stream>>>(
            Ain, H_, inwb + (size_t)l * 262144, H_, (float*)XPbf, 1024,
            H_, /*bf16 C*/2, nullptr, (l == 0) ? TPAD : 0, 12, 0);
        k_conv<<<NTOK * INNER_ / 256, 256, 0, stream>>>(
            XPbf, conv_w + l * INNER_ * 4, conv_b + l * INNER_, XCbf);
        gemm_mfma<64><<<dim3(128, 1), 256, 0, stream>>>(
            XCbf, INNER_, bpwb + (size_t)l * S_ * INNER_, INNER_, U, S_,
            INNER_, 0, nullptr, 0, 0, 0);
        k_scan_local<<<256, 64, 0, stream>>>(U, HEND);
        k_scan_apply<<<256, 64, 0, stream>>>(U, HEND);
        k_ymix<<<NTOK / 4, 256, 0, stream>>>(
            U, Cp_w + l * INNER_ * S_, Dw + l * INNER_, XCbf, XPbf);
        gemm_mfma<128><<<dim3(128, 2), 256, 0, stream>>>(
            XCbf, INNER_, outwb + (size_t)l * H_ * INNER_, INNER_, fouts[l], H_,
            INNER_, 0, nullptr, 0, 0, 0);
        k_ln<<<NTOK, 256, 0, stream>>>(fouts[l], fin, ln_g + l * H_, ln_b + l * H_,
                                       fouts[l], (l == 2) ? COMB : Fbf, (l == 2) ? 512 : 256);
        fin = fouts[l];
    }

    // pattern convs as shifted GEMMs over padded bf16 audio_emb
    gemm_mfma<128><<<dim3(128, 2), 256, 0, stream>>>(
        Apad, H_, w0b, H_, PATF, H_, H_, 0, pat_b, TPAD, 12, 0);
    gemm_mfma<64><<<dim3(128, 4), 256, 0, stream>>>(
        Apad, H_, wkb, H_, PATF, H_, H_, /*ACC*/1, nullptr, TPAD, 12, /*tap0*/1);
    gemm_mfma<64><<<dim3(128, 4), 256, 0, stream>>>(
        Apad, H_, wkb, H_, PATF, H_, H_, /*ACC*/1, nullptr, TPAD, 12, /*tap2*/2);
    k_pat2comb<<<16384, 256, 0, stream>>>(PATF, COMB);

    // fused projection: comb(N,512) @ fus_w(256,512)^T
    gemm_mfma<128><<<dim3(128, 2), 256, 0, stream>>>(
        COMB, 512, fuswb, 512, FUSP, H_, 512, 0, nullptr, 0, 0, 0);
    k_fusln<<<NTOK, 256, 0, stream>>>(FUSP, fus_b, fus_g, fus_bb, Fbf);

    // head: fused(N,256) @ head_w(4096,256)^T, epilogue remaps to (b,c,t,v) + bias
    gemm_mfma<128><<<dim3(128, 32), 256, 0, stream>>>(
        Fbf, H_, headwb, H_, (float*)d_out, V_, H_, /*head*/4, head_b, 0, 0, 0);
}

// Round 5
// 1285.291 us; speedup vs baseline: 2.4793x; 1.0164x over previous
//
#include <hip/hip_runtime.h>

#define B_ 4
#define C_ 4
#define T_ 4096
#define H_ 256
#define INNER_ 512
#define S_ 64
#define L_ 3
#define V_ 1024
#define NTOK (B_*T_)   // 16384
#define TPAD (T_+24)   // 4120: 12 zero rows each side per batch

typedef __attribute__((ext_vector_type(8))) short short8v;
typedef __attribute__((ext_vector_type(4))) short short4v;
typedef __attribute__((ext_vector_type(4))) float f32x4;

__device__ __forceinline__ float siluf(float x) { return x / (1.0f + expf(-x)); }

__device__ __forceinline__ unsigned short f2bf(float x) {
    unsigned u = __float_as_uint(x);
    u = (u + 0x7FFFu + ((u >> 16) & 1u)) >> 16;   // RNE
    return (unsigned short)u;
}
__device__ __forceinline__ float bf2f(unsigned short v) {
    return __uint_as_float(((unsigned)v) << 16);
}

// ============================ bf16 MFMA GEMM (pipelined) ===============================
// C(N,M) = A(N,K) * Bw(M,K)^T, A/B bf16, fp32 accum. Tile 128 x BN, BK=32, 4 waves.
// Pipeline: register-prefetch next K-step's global loads, compute current step's MFMAs
// while they are in flight, ds_write into the ALTERNATE LDS buffer -> ONE barrier/step.
// LDS fragment-major: frag f = 1KB, lane l reads 16B at f*1024 + l*16 (conflict-free);
// staging writes the matching permutation (also conflict-free).
// flags: 2 = C stored bf16, 4 = head epilogue (remap to (b,c,t,v) + bias).
// bstride/roff: batch-padded A addressing (row = (n0>>12)*bstride + (n0&4095) + roff).
// patmode==3: dilated pattern conv as 3-tap shifted GEMM, blockIdx.y = dilation group,
//             register accumulation across taps, Bg = [w0 (256x256) | wk (8x64x256)],
//             bias indexed with the GROUP offset (g*64) -- round-2 bugfix.
template<int BN>
__global__ __launch_bounds__(256) void gemm_mfma(
    const unsigned short* __restrict__ Ag, int lda,
    const unsigned short* __restrict__ Bg, int ldb,
    float* __restrict__ Cg, int ldc,
    int K, int flags, const float* __restrict__ bias,
    int bstride, int roff, int patmode)
{
    constexpr int FM  = (BN == 128) ? 4 : 2;
    constexpr int FN  = 4;
    constexpr int BCH = (BN == 128) ? 2 : 1;
    __shared__ __attribute__((aligned(16))) unsigned short Alds[2][128 * 32];
    __shared__ __attribute__((aligned(16))) unsigned short Blds[2][BN * 32];

    int tid = threadIdx.x;
    int wid = tid >> 6, lane = tid & 63;
    int qq = lane >> 4, l16 = lane & 15;
    int wm, wn;
    if (BN == 128) { wm = wid >> 1; wn = wid & 1; } else { wm = wid; wn = 0; }

    int n0 = blockIdx.x * 128;
    int g = blockIdx.y;
    int arow = tid >> 2, acb = tid & 3;              // staging: row 0..63 (+64), k-chunk

    int m0 = (patmode == 3) ? 0 : g * BN;
    float* Cb = (patmode == 3) ? (float*)((unsigned short*)Cg + 256 + g * 64) : Cg;
    const float* biasp = (patmode == 3 && bias) ? bias + g * 64 : bias;
    int d = (g == 0) ? 1 : (g == 1) ? 3 : (g == 2) ? 6 : 12;   // used only by patmode

    f32x4 acc[FM][FN] = {};
    int ntap = (patmode == 3) ? 3 : 1;

    for (int tap = 0; tap < ntap; ++tap) {
        const unsigned short* Bp;
        int ro;
        if (patmode == 3) {
            ro = 12 + (tap == 0 ? -d : (tap == 2 ? d : 0));
            Bp = (tap == 1) ? Bg + (size_t)g * (64 * 256)
                            : Bg + 65536 + (size_t)((g << 1) + (tap >> 1)) * (64 * 256);
        } else { ro = roff; Bp = Bg; }
        const unsigned short* Ab = Ag +
            (size_t)(bstride ? ((n0 >> 12) * bstride + (n0 & (T_ - 1)) + ro) : n0) * lda;

        // ---- prologue: load k0=0, stage into buf 0 ----
        short8v pa0, pa1, pb0, pb1;
        pa0 = *(const short8v*)(Ab + (size_t)arow * lda + acb * 8);
        pa1 = *(const short8v*)(Ab + (size_t)(arow + 64) * lda + acb * 8);
        pb0 = *(const short8v*)(Bp + (size_t)(m0 + arow) * ldb + acb * 8);
        if (BCH == 2)
            pb1 = *(const short8v*)(Bp + (size_t)(m0 + arow + 64) * ldb + acb * 8);
        __syncthreads();   // protect buffers from previous tap's readers
        {
            int f0 = (arow >> 4) * 512 + acb * 128 + (arow & 15) * 8;
            int r2 = arow + 64;
            int f1 = (r2 >> 4) * 512 + acb * 128 + (r2 & 15) * 8;
            *(short8v*)(&Alds[0][f0]) = pa0;
            *(short8v*)(&Alds[0][f1]) = pa1;
            *(short8v*)(&Blds[0][f0]) = pb0;
            if (BCH == 2) *(short8v*)(&Blds[0][f1]) = pb1;
        }
        __syncthreads();

        int cur = 0;
        for (int k0 = 32; k0 < K; k0 += 32) {
            // issue next step's global loads (stay in flight during MFMA)
            short8v na0, na1, nb0, nb1;
            na0 = *(const short8v*)(Ab + (size_t)arow * lda + k0 + acb * 8);
            na1 = *(const short8v*)(Ab + (size_t)(arow + 64) * lda + k0 + acb * 8);
            nb0 = *(const short8v*)(Bp + (size_t)(m0 + arow) * ldb + k0 + acb * 8);
            if (BCH == 2)
                nb1 = *(const short8v*)(Bp + (size_t)(m0 + arow + 64) * ldb + k0 + acb * 8);

            // compute current buffer
            {
                short8v afr[FM], bfr[FN];
#pragma unroll
                for (int i = 0; i < FM; ++i)
                    afr[i] = *(const short8v*)(&Alds[cur][(wm * FM + i) * 512 + lane * 8]);
#pragma unroll
                for (int j = 0; j < FN; ++j)
                    bfr[j] = *(const short8v*)(&Blds[cur][(wn * FN + j) * 512 + lane * 8]);
#pragma unroll
                for (int i = 0; i < FM; ++i)
#pragma unroll
                    for (int j = 0; j < FN; ++j)
                        acc[i][j] = __builtin_amdgcn_mfma_f32_16x16x32_bf16(afr[i], bfr[j], acc[i][j], 0, 0, 0);
            }

            // stage next step into the alternate buffer (vmcnt wait lands here)
            {
                int f0 = (arow >> 4) * 512 + acb * 128 + (arow & 15) * 8;
                int r2 = arow + 64;
                int f1 = (r2 >> 4) * 512 + acb * 128 + (r2 & 15) * 8;
                *(short8v*)(&Alds[cur ^ 1][f0]) = na0;
                *(short8v*)(&Alds[cur ^ 1][f1]) = na1;
                *(short8v*)(&Blds[cur ^ 1][f0]) = nb0;
                if (BCH == 2) *(short8v*)(&Blds[cur ^ 1][f1]) = nb1;
            }
            __syncthreads();
            cur ^= 1;
        }
        // final step
        {
            short8v afr[FM], bfr[FN];
#pragma unroll
            for (int i = 0; i < FM; ++i)
                afr[i] = *(const short8v*)(&Alds[cur][(wm * FM + i) * 512 + lane * 8]);
#pragma unroll
            for (int j = 0; j < FN; ++j)
                bfr[j] = *(const short8v*)(&Blds[cur][(wn * FN + j) * 512 + lane * 8]);
#pragma unroll
            for (int i = 0; i < FM; ++i)
#pragma unroll
                for (int j = 0; j < FN; ++j)
                    acc[i][j] = __builtin_amdgcn_mfma_f32_16x16x32_bf16(afr[i], bfr[j], acc[i][j], 0, 0, 0);
        }
    } // taps

#pragma unroll
    for (int i = 0; i < FM; ++i) {
#pragma unroll
        for (int r = 0; r < 4; ++r) {
            int row = n0 + wm * (FM * 16) + i * 16 + qq * 4 + r;
#pragma unroll
            for (int j = 0; j < FN; ++j) {
                int col = m0 + wn * (FN * 16) + j * 16 + l16;
                float v = acc[i][j][r];
                if (biasp) v += biasp[col];
                if (flags & 4) {                       // head: out[b,c,t,v]
                    int bb2 = row >> 12, t = row & (T_ - 1);
                    int cc = col >> 10, vv = col & (V_ - 1);
                    Cg[((size_t)(((bb2 << 2) + cc) << 12) + t) * V_ + vv] = v;
                } else if (flags & 2) {                // bf16 C
                    ((unsigned short*)Cb)[(size_t)row * ldc + col] = f2bf(v);
                } else {
                    Cb[(size_t)row * ldc + col] = v;
                }
            }
        }
    }
}

// ---------------- embedding: fp32 A + bf16 padded copy for GEMM/pat --------------------
__global__ __launch_bounds__(256) void k_embed(
    const int* __restrict__ tok, const float* __restrict__ text,
    const float* __restrict__ tok_emb, const float* __restrict__ pos_emb,
    const int* __restrict__ pos_off, float* __restrict__ A, unsigned short* __restrict__ Apad)
{
    int gid = blockIdx.x * 256 + threadIdx.x;
    int h = gid & (H_ - 1);
    int n = gid >> 8;
    int b = n >> 12, t = n & (T_ - 1);
    float acc = 0.f;
#pragma unroll
    for (int c = 0; c < C_; ++c) {
        int tk = tok[((b * C_ + c) << 12) + t];
        acc += tok_emb[(c * V_ + tk) * H_ + h];
    }
    int po = pos_off[0];
    acc = acc * 0.25f + pos_emb[(po + t) * H_ + h] + text[b * H_ + h];
    A[(size_t)n * H_ + h] = acc;
    Apad[((size_t)b * TPAD + 12 + t) * H_ + h] = f2bf(acc);
}

__global__ void k_zeropad(unsigned short* __restrict__ Apad)
{
    int blk = blockIdx.x;                 // 96 = 4 batches * 24 pad rows
    int b = blk / 24, rw = blk % 24;
    int rr = rw < 12 ? rw : T_ + rw;      // rows 0..11 and 4108..4119
    Apad[((size_t)b * TPAD + rr) * H_ + threadIdx.x] = 0;
}

// ---------------- all weight fp32 -> bf16 conversions in one kernel --------------------
__global__ __launch_bounds__(256) void k_wconv(
    const float* __restrict__ inw, const float* __restrict__ outw,
    const float* __restrict__ bpw, const float* __restrict__ fusw,
    const float* __restrict__ headw,
    unsigned short* __restrict__ dinw, unsigned short* __restrict__ doutw,
    unsigned short* __restrict__ dbpw, unsigned short* __restrict__ dfusw,
    unsigned short* __restrict__ dheadw)
{
    int i = blockIdx.x * 256 + threadIdx.x;       // total 2,457,600
    if (i < 786432)        dinw[i] = f2bf(inw[i]);
    else if (i < 1179648)  doutw[i - 786432]  = f2bf(outw[i - 786432]);
    else if (i < 1277952)  dbpw[i - 1179648]  = f2bf(bpw[i - 1179648]);
    else if (i < 1409024)  dfusw[i - 1277952] = f2bf(fusw[i - 1277952]);
    else                   dheadw[i - 1409024] = f2bf(headw[i - 1409024]);
}

// pack pat weights: w0[oc][cin] = pw[...,k=1]; wk[g][o][cin], g = id*2 + (k==2)
__global__ __launch_bounds__(256) void k_pack_pat(
    const float* __restrict__ pw, unsigned short* __restrict__ w0,
    unsigned short* __restrict__ wk)
{
    int idx = blockIdx.x * 256 + threadIdx.x;     // 65536 + 131072
    if (idx < 65536) {
        int oc = idx >> 8, cin = idx & 255;
        w0[idx] = f2bf(pw[(oc * 256 + cin) * 3 + 1]);
    } else {
        int j = idx - 65536;
        int g = j >> 14, o = (j >> 8) & 63, cin = j & 255;
        int id = g >> 1, kk = (g & 1) * 2;
        wk[j] = f2bf(pw[((id * 64 + o) * 256 + cin) * 3 + kk]);
    }
}

// ---------------- causal depthwise conv4 + bias + silu (bf16, 4 ch/thread) -------------
__global__ __launch_bounds__(256) void k_conv(
    const unsigned short* __restrict__ XPb, const float* __restrict__ cw,
    const float* __restrict__ cb, unsigned short* __restrict__ XCb)
{
    int gid = blockIdx.x * 256 + threadIdx.x;     // NTOK * 128 threads
    int i4 = (gid & 127) << 2;
    int n = gid >> 7;
    int b = n >> 12, t = n & (T_ - 1);
    float acc[4];
#pragma unroll
    for (int j = 0; j < 4; ++j) acc[j] = cb[i4 + j];
#pragma unroll
    for (int k = 0; k < 4; ++k) {
        int tt = t - 3 + k;
        if (tt >= 0) {
            short4v v = *(const short4v*)(XPb + (size_t)((b << 12) + tt) * 1024 + i4);
#pragma unroll
            for (int j = 0; j < 4; ++j)
                acc[j] += bf2f((unsigned short)v[j]) * cw[(i4 + j) * 4 + k];
        }
    }
    short4v o;
#pragma unroll
    for (int j = 0; j < 4; ++j) o[j] = (short)f2bf(siluf(acc[j]));
    *(short4v*)(XCb + (size_t)n * INNER_ + i4) = o;
}

// ---------------- chunked parallel EWMA scan -------------------------------------------
__global__ void k_scan_local(float* __restrict__ U, float* __restrict__ hend)
{
    int blk = blockIdx.x;                 // 256 = 4 batches * 64 chunks
    int b = blk >> 6, c = blk & 63;
    int s = threadIdx.x;                  // 64
    float* p = U + ((size_t)(b << 12) + c * 64) * 64 + s;
    float h = 0.f;
#pragma unroll 4
    for (int t = 0; t < 64; ++t) { h = 0.95f * h + 0.05f * p[t * 64]; p[t * 64] = h; }
    hend[(size_t)blk * 64 + s] = h;
}

__global__ void k_scan_apply(float* __restrict__ U, const float* __restrict__ hend)
{
    int blk = blockIdx.x;
    int b = blk >> 6, c = blk & 63;
    int s = threadIdx.x;
    if (c == 0) return;
    const float F = 0.03752414f;          // 0.95^64
    float Hc = 0.f;
    for (int cc = 0; cc < c; ++cc) Hc = hend[(size_t)((b << 6) + cc) * 64 + s] + F * Hc;
    float* p = U + ((size_t)(b << 12) + c * 64) * 64 + s;
    float w = 0.95f;
#pragma unroll 4
    for (int t = 0; t < 64; ++t) { p[t * 64] += w * Hc; w *= 0.95f; }
}

// ---------------- y2 = (hs@Cp^T + D*xc) * silu(xg), bf16 in place over XC --------------
__global__ __launch_bounds__(256) void k_ymix(
    const float* __restrict__ HS, const float* __restrict__ Cp,
    const float* __restrict__ Dp, unsigned short* __restrict__ XCb,
    const unsigned short* __restrict__ XPb)
{
    const int NB = 4;
    int n0 = blockIdx.x * NB;
    __shared__ float hsL[NB * 64];
    int tid = threadIdx.x;
    {
        int nn = tid >> 6, s = tid & 63;
        hsL[tid] = HS[(size_t)(n0 + nn) * 64 + s];
    }
    __syncthreads();
#pragma unroll
    for (int half = 0; half < 2; ++half) {
        int i = tid + half * 256;
        float acc[NB] = {};
        const float* cp = Cp + i * 64;
        for (int s = 0; s < 64; ++s) {
            float w = cp[s];
#pragma unroll
            for (int nn = 0; nn < NB; ++nn) acc[nn] += hsL[nn * 64 + s] * w;
        }
        float d = Dp[i];
#pragma unroll
        for (int nn = 0; nn < NB; ++nn) {
            size_t n = n0 + nn;
            float xc = bf2f(XCb[n * INNER_ + i]);
            float xg = bf2f(XPb[n * 1024 + 512 + i]);
            XCb[n * INNER_ + i] = f2bf((acc[nn] + d * xc) * siluf(xg));
        }
    }
}

// ---------------- residual + LayerNorm, fp32 out + bf16 copy ---------------------------
__global__ __launch_bounds__(256) void k_ln(
    const float* __restrict__ Yo, const float* __restrict__ Xin,
    const float* __restrict__ g, const float* __restrict__ bb,
    float* __restrict__ Out, unsigned short* __restrict__ Obf, int obfld)
{
    int n = blockIdx.x, h = threadIdx.x;
    float x = Yo[(size_t)n * H_ + h] + Xin[(size_t)n * H_ + h];
    float s = x, sq = x * x;
#pragma unroll
    for (int off = 32; off >= 1; off >>= 1) {
        s  += __shfl_down(s, off, 64);
        sq += __shfl_down(sq, off, 64);
    }
    __shared__ float rs[4], rq[4];
    int wid = h >> 6, lane = h & 63;
    if (lane == 0) { rs[wid] = s; rq[wid] = sq; }
    __syncthreads();
    float S = rs[0] + rs[1] + rs[2] + rs[3];
    float Q = rq[0] + rq[1] + rq[2] + rq[3];
    float m = S * (1.f / H_);
    float v = fmaxf(Q * (1.f / H_) - m * m, 0.f);
    float r = rsqrtf(v + 1e-5f);
    float y = (x - m) * r * g[h] + bb[h];
    Out[(size_t)n * H_ + h] = y;
    Obf[(size_t)n * obfld + h] = f2bf(y);
}

// ---------------- relu(pre + fus_b) then LN, bf16 out ----------------------------------
__global__ __launch_bounds__(256) void k_fusln(
    const float* __restrict__ Pre, const float* __restrict__ fb,
    const float* __restrict__ fg, const float* __restrict__ fbb,
    unsigned short* __restrict__ Outb)
{
    int n = blockIdx.x, h = threadIdx.x;
    float x = fmaxf(Pre[(size_t)n * H_ + h] + fb[h], 0.f);
    float s = x, sq = x * x;
#pragma unroll
    for (int off = 32; off >= 1; off >>= 1) {
        s  += __shfl_down(s, off, 64);
        sq += __shfl_down(sq, off, 64);
    }
    __shared__ float rs[4], rq[4];
    int wid = h >> 6, lane = h & 63;
    if (lane == 0) { rs[wid] = s; rq[wid] = sq; }
    __syncthreads();
    float S = rs[0] + rs[1] + rs[2] + rs[3];
    float Q = rq[0] + rq[1] + rq[2] + rq[3];
    float m = S * (1.f / H_);
    float v = fmaxf(Q * (1.f / H_) - m * m, 0.f);
    float r = rsqrtf(v + 1e-5f);
    Outb[(size_t)n * H_ + h] = f2bf((x - m) * r * fg[h] + fbb[h]);
}

extern "C" void kernel_launch(void* const* d_in, const int* in_sizes, int n_in,
                              void* d_out, int out_size, void* d_ws, size_t ws_size,
                              hipStream_t stream)
{
    (void)in_sizes; (void)n_in; (void)out_size; (void)ws_size;
    const int*   tok      = (const int*)d_in[0];
    const float* text     = (const float*)d_in[1];
    const float* tok_emb  = (const float*)d_in[2];
    const float* pos_emb  = (const float*)d_in[3];
    const float* in_w     = (const float*)d_in[4];
    const float* conv_w   = (const float*)d_in[5];
    const float* conv_b   = (const float*)d_in[6];
    const float* Dw       = (const float*)d_in[7];
    const float* Bp_w     = (const float*)d_in[8];
    const float* Cp_w     = (const float*)d_in[9];
    const float* out_w    = (const float*)d_in[10];
    const float* ln_g     = (const float*)d_in[11];
    const float* ln_b     = (const float*)d_in[12];
    const float* pat_w    = (const float*)d_in[13];
    const float* pat_b    = (const float*)d_in[14];
    const float* fus_w    = (const float*)d_in[15];
    const float* fus_b    = (const float*)d_in[16];
    const float* fus_g    = (const float*)d_in[17];
    const float* fus_bb   = (const float*)d_in[18];
    const float* head_w   = (const float*)d_in[19];
    const float* head_b   = (const float*)d_in[20];
    const int*   pos_off  = (const int*)d_in[21];

    float* W = (float*)d_ws;
    float* Abuf = W;                                              // 4,194,304 f
    float* F0   = W + 4194304;                                    // 4,194,304 f
    float* F1   = W + 8388608;                                    // 4,194,304 f
    float* U    = W + 12582912;                                   // 1,048,576 f
    float* HEND = W + 13631488;                                   //    16,384 f
    unsigned short* XPbf = (unsigned short*)(W + 13647872);       // 16,777,216 bf16
    unsigned short* XCbf = (unsigned short*)(W + 22036480);       //  8,388,608 bf16
    unsigned short* Fbf  = (unsigned short*)(W + 26230784);       //  4,194,304 bf16
    unsigned short* COMB = (unsigned short*)(W + 28327936);       //  8,388,608 bf16
    unsigned short* Apad = (unsigned short*)(W + 32522240);       //  4,218,880 bf16
    float* FUSP = W + 13647872;            // reuse XPbf region (dead after mamba loop)
    unsigned short* inwb   = (unsigned short*)(W + 34631680);     //   786,432 bf16
    unsigned short* outwb  = (unsigned short*)(W + 35024896);     //   393,216 bf16
    unsigned short* bpwb   = (unsigned short*)(W + 35221504);     //    98,304 bf16
    unsigned short* fuswb  = (unsigned short*)(W + 35270656);     //   131,072 bf16
    unsigned short* headwb = (unsigned short*)(W + 35336192);     // 1,048,576 bf16
    unsigned short* w0b    = (unsigned short*)(W + 35860480);     //    65,536 bf16 (wk follows contiguously)
    unsigned short* wkb    = (unsigned short*)(W + 35893248);     //   131,072 bf16
    // total 35,958,784 floats = 137.2 MiB

    k_embed<<<NTOK * H_ / 256, 256, 0, stream>>>(tok, text, tok_emb, pos_emb, pos_off, Abuf, Apad);
    k_zeropad<<<96, 256, 0, stream>>>(Apad);
    k_wconv<<<9600, 256, 0, stream>>>(in_w, out_w, Bp_w, fus_w, head_w,
                                      inwb, outwb, bpwb, fuswb, headwb);
    k_pack_pat<<<768, 256, 0, stream>>>(pat_w, w0b, wkb);

    const float* fin = Abuf;
    float* fouts[3] = {F0, F1, F0};
    for (int l = 0; l < L_; ++l) {
        const unsigned short* Ain = (l == 0) ? Apad : Fbf;
        gemm_mfma<128><<<dim3(128, 8), 256, 0, stream>>>(
            Ain, H_, inwb + (size_t)l * 262144, H_, (float*)XPbf, 1024,
            H_, /*bf16 C*/2, nullptr, (l == 0) ? TPAD : 0, 12, 0);
        k_conv<<<NTOK * 128 / 256, 256, 0, stream>>>(
            XPbf, conv_w + l * INNER_ * 4, conv_b + l * INNER_, XCbf);
        gemm_mfma<64><<<dim3(128, 1), 256, 0, stream>>>(
            XCbf, INNER_, bpwb + (size_t)l * S_ * INNER_, INNER_, U, S_,
            INNER_, 0, nullptr, 0, 0, 0);
        k_scan_local<<<256, 64, 0, stream>>>(U, HEND);
        k_scan_apply<<<256, 64, 0, stream>>>(U, HEND);
        k_ymix<<<NTOK / 4, 256, 0, stream>>>(
            U, Cp_w + l * INNER_ * S_, Dw + l * INNER_, XCbf, XPbf);
        gemm_mfma<128><<<dim3(128, 2), 256, 0, stream>>>(
            XCbf, INNER_, outwb + (size_t)l * H_ * INNER_, INNER_, fouts[l], H_,
            INNER_, 0, nullptr, 0, 0, 0);
        k_ln<<<NTOK, 256, 0, stream>>>(fouts[l], fin, ln_g + l * H_, ln_b + l * H_,
                                       fouts[l], (l == 2) ? COMB : Fbf, (l == 2) ? 512 : 256);
        fin = fouts[l];
    }

    // pattern convs: single fused 3-tap shifted GEMM, bf16 output into COMB cols 256..511
    gemm_mfma<64><<<dim3(128, 4), 256, 0, stream>>>(
        Apad, H_, w0b, H_, (float*)COMB, 512, H_, /*bf16 C*/2, pat_b, TPAD, 12, /*pat*/3);

    // fused projection: comb(N,512) @ fus_w(256,512)^T
    gemm_mfma<128><<<dim3(128, 2), 256, 0, stream>>>(
        COMB, 512, fuswb, 512, FUSP, H_, 512, 0, nullptr, 0, 0, 0);
    k_fusln<<<NTOK, 256, 0, stream>>>(FUSP, fus_b, fus_g, fus_bb, Fbf);

    // head: fused(N,256) @ head_w(4096,256)^T, epilogue remaps to (b,c,t,v) + bias
    gemm_mfma<128><<<dim3(128, 32), 256, 0, stream>>>(
        Fbf, H_, headwb, H_, (float*)d_out, V_, H_, /*head*/4, head_b, 0, 0, 0);
}